// Round 13
// baseline (665.356 us; speedup 1.0000x reference)
//
#include <hip/hip_runtime.h>
#include <cstdint>
#include <cstddef>

typedef __attribute__((ext_vector_type(8))) short short8;
typedef __attribute__((ext_vector_type(4))) float f32x4;
typedef unsigned short u16;

#define CDIM 384

__device__ __forceinline__ u16 f2bf(float f) {
  union { float f; uint32_t u; } v; v.f = f;
  return (u16)((v.u + 0x7FFFu + ((v.u >> 16) & 1u)) >> 16);
}

// async global->LDS, 16B per lane (m97 pattern: linear LDS dest = wave base + lane*16)
__device__ __forceinline__ void glds16(const void* g, void* l) {
  __builtin_amdgcn_global_load_lds(
      (__attribute__((address_space(1))) void*)(g),
      (__attribute__((address_space(3))) void*)(l), 16, 0, 0);
}

// bijective XCD-chunking swizzle (m204): contiguous new-ids land on one XCD
__device__ __forceinline__ int xcd_swz(int orig, int nwg) {
  int q = nwg >> 3, r = nwg & 7;
  int x = orig & 7, i = orig >> 3;
  int base = (x < r) ? x * (q + 1) : r * (q + 1) + (x - r) * q;
  return base + i;
}

// ---- weight convert + transpose: Wt[n*K + k] = bf16(W[k*N + n]) ----
__global__ void wconv_t(const float* __restrict__ W, u16* __restrict__ Wt, int K, int N) {
  int i = blockIdx.x * 256 + threadIdx.x;
  if (i >= K * N) return;
  int k = i / N, n = i - k * N;
  Wt[(size_t)n * K + k] = f2bf(W[i]);
}

// ---- LayerNorm over 384, one wave per row; optional shift+window gather ----
template<bool GATHER>
__global__ __launch_bounds__(256) void ln_kernel(const float* __restrict__ X,
    const float* __restrict__ G, const float* __restrict__ Bp,
    u16* __restrict__ Y) {
  int wid = threadIdx.x >> 6, lane = threadIdx.x & 63;
  int row = blockIdx.x * 4 + wid;
  const float* xr = X + (size_t)row * CDIM;
  float4 a = ((const float4*)xr)[lane];
  float2 b = ((const float2*)xr)[128 + lane];
  float s1 = a.x + a.y + a.z + a.w + b.x + b.y;
  float s2 = a.x*a.x + a.y*a.y + a.z*a.z + a.w*a.w + b.x*b.x + b.y*b.y;
  #pragma unroll
  for (int m = 1; m < 64; m <<= 1) { s1 += __shfl_xor(s1, m, 64); s2 += __shfl_xor(s2, m, 64); }
  float mean = s1 * (1.0f / CDIM);
  float var  = s2 * (1.0f / CDIM) - mean * mean;
  float rstd = rsqrtf(var + 1e-5f);
  float4 g4 = ((const float4*)G)[lane];
  float2 g2 = ((const float2*)G)[128 + lane];
  float4 b4 = ((const float4*)Bp)[lane];
  float2 b2 = ((const float2*)Bp)[128 + lane];
  size_t orow = row;
  if (GATHER) {
    int bb = row / 3136, l = row - bb * 3136;
    int h = l / 56, w = l - h * 56;
    int hs = h - 3; if (hs < 0) hs += 56;
    int wsv = w - 3; if (wsv < 0) wsv += 56;
    int wi = (hs / 7) * 8 + (wsv / 7);
    int n = (hs % 7) * 7 + (wsv % 7);
    orow = (size_t)(bb * 64 + wi) * 49 + n;
  }
  u16* yr = Y + orow * CDIM;
  ushort4 o4;
  o4.x = f2bf((a.x - mean) * rstd * g4.x + b4.x);
  o4.y = f2bf((a.y - mean) * rstd * g4.y + b4.y);
  o4.z = f2bf((a.z - mean) * rstd * g4.z + b4.z);
  o4.w = f2bf((a.w - mean) * rstd * g4.w + b4.w);
  ((ushort4*)yr)[lane] = o4;
  ushort2 o2;
  o2.x = f2bf((b.x - mean) * rstd * g2.x + b2.x);
  o2.y = f2bf((b.y - mean) * rstd * g2.y + b2.y);
  ((ushort2*)yr)[128 + lane] = o2;
}

// ---- bf16 GEMM, A (M,K) row-major, Bt (N,K) row-major, 128x128 tile, BK=32 ----
// T3+T4 minimum: double-buffered glds16 prefetch with COUNTED vmcnt + raw
// s_barrier — next-tile loads stay in flight across the barriers (never
// drained to 0 in the main loop).
// MODE 0: qkv scatter (bf16)   1: proj + x residual, window->token scatter (f32)
// MODE 2: GELU -> hidden bf16  3: + xres residual -> f32 out
template<int MODE>
__global__ __launch_bounds__(256) void gemm_bt(
    const u16* __restrict__ A, const u16* __restrict__ Bt,
    const float* __restrict__ bias, const float* __restrict__ extra,
    void* __restrict__ outp, int K) {
  __shared__ __align__(16) u16 As[2][4096];
  __shared__ __align__(16) u16 Bs[2][4096];
  int tid = threadIdx.x;
  int lane = tid & 63, wid = tid >> 6;
  int ln = lane & 15, g = lane >> 4;
  int wm = (wid >> 1) * 64, wn = (wid & 1) * 64;
  int gx = gridDim.x;
  int nwg = gx * gridDim.y;
  int id = xcd_swz(blockIdx.y * gx + blockIdx.x, nwg);
  int bn = id % gx, bm = id / gx;
  int rs = K >> 3;  // short8 per row
  const short8* Ag = (const short8*)(A + (size_t)bm * 128 * K);
  const short8* Bg = (const short8*)(Bt + (size_t)bn * 128 * K);
  int c0 = tid, c1 = tid + 256;
  int r0 = c0 >> 2, q0 = c0 & 3, r1 = c1 >> 2, q1 = c1 & 3;
  f32x4 acc[4][4] = {};
  int nk = K >> 5;
  // prologue: issue tile-0 staging (4 loads in flight)
  glds16(&Ag[r0 * rs + q0], &((short8*)As[0])[c0]);
  glds16(&Ag[r1 * rs + q1], &((short8*)As[0])[c1]);
  glds16(&Bg[r0 * rs + q0], &((short8*)Bs[0])[c0]);
  glds16(&Bg[r1 * rs + q1], &((short8*)Bs[0])[c1]);
  int cur = 0;
  for (int kt = 0; kt < nk; ++kt) {
    bool pf = (kt + 1 < nk);
    if (pf) {
      int ko = (kt + 1) * 4;
      glds16(&Ag[r0 * rs + ko + q0], &((short8*)As[cur ^ 1])[c0]);
      glds16(&Ag[r1 * rs + ko + q1], &((short8*)As[cur ^ 1])[c1]);
      glds16(&Bg[r0 * rs + ko + q0], &((short8*)Bs[cur ^ 1])[c0]);
      glds16(&Bg[r1 * rs + ko + q1], &((short8*)Bs[cur ^ 1])[c1]);
    }
    // wait ONLY for the current tile's 4 loads (oldest); the 4 just-issued
    // prefetch loads remain in flight across both barriers (T4).
    if (pf) asm volatile("s_waitcnt vmcnt(4)" ::: "memory");
    else    asm volatile("s_waitcnt vmcnt(0)" ::: "memory");
    __builtin_amdgcn_s_barrier();   // all waves: cur tile resident in LDS
    short8 af[4], bf[4];
    #pragma unroll
    for (int mi = 0; mi < 4; ++mi) af[mi] = ((short8*)As[cur])[(wm + mi * 16 + ln) * 4 + g];
    #pragma unroll
    for (int ni = 0; ni < 4; ++ni) bf[ni] = ((short8*)Bs[cur])[(wn + ni * 16 + ln) * 4 + g];
    #pragma unroll
    for (int mi = 0; mi < 4; ++mi)
      #pragma unroll
      for (int ni = 0; ni < 4; ++ni)
        acc[mi][ni] = __builtin_amdgcn_mfma_f32_16x16x32_bf16(af[mi], bf[ni], acc[mi][ni], 0, 0, 0);
    // my ds_reads are complete (lgkm 0) -> after barrier, next iter may
    // safely overwrite buf[cur] with its prefetch.
    asm volatile("s_waitcnt lgkmcnt(0)" ::: "memory");
    __builtin_amdgcn_s_barrier();
    cur ^= 1;
  }
  int Rbase = bm * 128 + wm + g * 4;
  int Cbase = bn * 128 + wn + ln;
  #pragma unroll
  for (int mi = 0; mi < 4; ++mi) {
    #pragma unroll
    for (int r = 0; r < 4; ++r) {
      int R = Rbase + mi * 16 + r;
      #pragma unroll
      for (int ni = 0; ni < 4; ++ni) {
        int Cc = Cbase + ni * 16;
        float v = acc[mi][ni][r] + bias[Cc];
        if (MODE == 0) {
          int w_ = R / 49, n = R - w_ * 49;
          int t = Cc / 384, rem = Cc - t * 384;
          int hh = rem >> 5, d = rem & 31;
          ((u16*)outp)[((size_t)(w_ * 3 + t) * 12 + hh) * 1568 + n * 32 + d] = f2bf(v);
        } else if (MODE == 1) {
          int w_ = R / 49, n = R - w_ * 49;
          int bb = w_ >> 6, wi = w_ & 63;
          int hs = (wi >> 3) * 7 + n / 7;
          int wsv = (wi & 7) * 7 + n % 7;
          int h2 = hs + 3; if (h2 >= 56) h2 -= 56;
          int w2 = wsv + 3; if (w2 >= 56) w2 -= 56;
          size_t idx = ((size_t)bb * 3136 + h2 * 56 + w2) * 384 + Cc;
          ((float*)outp)[idx] = extra[idx] + v;
        } else if (MODE == 2) {
          float gl = 0.5f * v * (1.0f + erff(v * 0.70710678118f));
          ((u16*)outp)[(size_t)R * 1536 + Cc] = f2bf(gl);
        } else {
          size_t idx = (size_t)R * 384 + Cc;
          ((float*)outp)[idx] = extra[idx] + v;
        }
      }
    }
  }
}

// ---- attention: 1 wave per (window, head); S^T = K*Q^T; O^T = V^T*P^T ----
__global__ __launch_bounds__(128) void attn_kernel(
    const u16* __restrict__ qkv, const float* __restrict__ rpb,
    u16* __restrict__ aout) {
  __shared__ __align__(16) u16 lds[2][10240];
  int wid = threadIdx.x >> 6, lane = threadIdx.x & 63;
  int task = blockIdx.x * 2 + wid;
  int w_ = task / 12, hh = task - w_ * 12;
  int wi = w_ & 63;
  u16* Q  = lds[wid];
  u16* Kt = Q + 2048;
  u16* Vt = Q + 4096;
  u16* P  = Q + 6144;
  const short8* qb = (const short8*)(qkv + ((size_t)w_ * 36 + hh) * 1568);
  const short8* kb = (const short8*)(qkv + ((size_t)w_ * 36 + 12 + hh) * 1568);
  const short8* vb = (const short8*)(qkv + ((size_t)w_ * 36 + 24 + hh) * 1568);
  short8 zz = {0, 0, 0, 0, 0, 0, 0, 0};
  for (int c = 196 + lane; c < 256; c += 64) { ((short8*)Q)[c] = zz; ((short8*)Kt)[c] = zz; }
  for (int c = lane; c < 256; c += 64) ((short8*)Vt)[c] = zz;
  __syncthreads();
  for (int c = lane; c < 196; c += 64) {
    ((short8*)Q)[c]  = qb[c];
    ((short8*)Kt)[c] = kb[c];
    short8 vv = vb[c];
    int n = c >> 2, d0 = (c & 3) << 3;
    #pragma unroll
    for (int j = 0; j < 8; ++j) Vt[(d0 + j) * 64 + n] = (u16)vv[j];
  }
  __syncthreads();
  int ln = lane & 15, g = lane >> 4;
  short8 ak[4], bq[4];
  #pragma unroll
  for (int mi = 0; mi < 4; ++mi) ak[mi] = ((const short8*)Kt)[(mi * 16 + ln) * 4 + g];
  #pragma unroll
  for (int ni = 0; ni < 4; ++ni) bq[ni] = ((const short8*)Q)[(ni * 16 + ln) * 4 + g];
  f32x4 zf = {0.f, 0.f, 0.f, 0.f};
  f32x4 s[4][4];
  #pragma unroll
  for (int mi = 0; mi < 4; ++mi)
    #pragma unroll
    for (int ni = 0; ni < 4; ++ni)
      s[mi][ni] = __builtin_amdgcn_mfma_f32_16x16x32_bf16(ak[mi], bq[ni], zf, 0, 0, 0);
  const float scale = 0.17677669529663687f;  // 1/sqrt(32)
  int hb = (wi >> 3) * 7, wb = (wi & 7) * 7;
  #pragma unroll
  for (int ni = 0; ni < 4; ++ni) {
    int n = ni * 16 + ln;
    bool nv = n < 49;
    int nh = n / 7, nw = n - nh * 7;
    int hsn = hb + nh, wsn = wb + nw;
    int rn = (hsn < 49 ? 0 : (hsn < 53 ? 1 : 2)) * 3 + (wsn < 49 ? 0 : (wsn < 53 ? 1 : 2));
    float pv[16];
    float mx = -3.0e38f;
    #pragma unroll
    for (int mi = 0; mi < 4; ++mi) {
      #pragma unroll
      for (int r = 0; r < 4; ++r) {
        int m = mi * 16 + g * 4 + r;
        float v = -1.0e9f;
        if (nv && m < 49) {
          int mh = m / 7, mw = m - mh * 7;
          int hsm = hb + mh, wsm = wb + mw;
          int rm = (hsm < 49 ? 0 : (hsm < 53 ? 1 : 2)) * 3 + (wsm < 49 ? 0 : (wsm < 53 ? 1 : 2));
          int rel = (nh - mh + 6) * 13 + (nw - mw + 6);
          v = s[mi][ni][r] * scale + rpb[rel * 12 + hh];
          if (rn != rm) v -= 100.0f;
        }
        pv[mi * 4 + r] = v;
        mx = fmaxf(mx, v);
      }
    }
    mx = fmaxf(mx, __shfl_xor(mx, 16, 64));
    mx = fmaxf(mx, __shfl_xor(mx, 32, 64));
    float sum = 0.f;
    #pragma unroll
    for (int i = 0; i < 16; ++i) { pv[i] = __expf(pv[i] - mx); sum += pv[i]; }
    sum += __shfl_xor(sum, 16, 64);
    sum += __shfl_xor(sum, 32, 64);
    float inv = 1.0f / sum;
    #pragma unroll
    for (int mi = 0; mi < 4; ++mi) {
      ushort4 pk;
      pk.x = f2bf(pv[mi * 4 + 0] * inv);
      pk.y = f2bf(pv[mi * 4 + 1] * inv);
      pk.z = f2bf(pv[mi * 4 + 2] * inv);
      pk.w = f2bf(pv[mi * 4 + 3] * inv);
      *(ushort4*)(P + n * 64 + mi * 16 + g * 4) = pk;
    }
  }
  __syncthreads();
  f32x4 o[2][4] = {};
  #pragma unroll
  for (int kt = 0; kt < 2; ++kt) {
    short8 av[2], bp[4];
    #pragma unroll
    for (int m2 = 0; m2 < 2; ++m2) av[m2] = ((const short8*)Vt)[(m2 * 16 + ln) * 8 + kt * 4 + g];
    #pragma unroll
    for (int ni = 0; ni < 4; ++ni) bp[ni] = ((const short8*)P)[(ni * 16 + ln) * 8 + kt * 4 + g];
    #pragma unroll
    for (int m2 = 0; m2 < 2; ++m2)
      #pragma unroll
      for (int ni = 0; ni < 4; ++ni)
        o[m2][ni] = __builtin_amdgcn_mfma_f32_16x16x32_bf16(av[m2], bp[ni], o[m2][ni], 0, 0, 0);
  }
  #pragma unroll
  for (int m2 = 0; m2 < 2; ++m2)
    #pragma unroll
    for (int ni = 0; ni < 4; ++ni)
      #pragma unroll
      for (int r = 0; r < 4; ++r) {
        int d = m2 * 16 + g * 4 + r;
        int n = ni * 16 + ln;
        if (n < 49)
          aout[((size_t)w_ * 49 + n) * 384 + hh * 32 + d] = f2bf(o[m2][ni][r]);
      }
}

extern "C" void kernel_launch(void* const* d_in, const int* in_sizes, int n_in,
                              void* d_out, int out_size, void* d_ws, size_t ws_size,
                              hipStream_t stream) {
  const float* x     = (const float*)d_in[0];
  const float* n1g   = (const float*)d_in[3];
  const float* n1b   = (const float*)d_in[4];
  const float* qkvw  = (const float*)d_in[5];
  const float* qkvb  = (const float*)d_in[6];
  const float* rpb   = (const float*)d_in[7];
  const float* projw = (const float*)d_in[8];
  const float* projb = (const float*)d_in[9];
  const float* n2g   = (const float*)d_in[10];
  const float* n2b   = (const float*)d_in[11];
  const float* w1    = (const float*)d_in[12];
  const float* b1    = (const float*)d_in[13];
  const float* w2    = (const float*)d_in[14];
  const float* b2    = (const float*)d_in[15];

  char* ws = (char*)d_ws;
  u16* wqT    = (u16*)(ws + 0);           // 1152x384
  u16* wpT    = (u16*)(ws + 884736);      // 384x384
  u16* w1T    = (u16*)(ws + 1179648);     // 1536x384
  u16* w2T    = (u16*)(ws + 2359296);     // 384x1536
  u16* lnbuf  = (u16*)(ws + 3538944);     // 50176x384 bf16
  u16* qkvB   = (u16*)(ws + 42074112);    // 1024x3x12x49x32 bf16
  u16* attnO  = (u16*)(ws + 157679616);   // 50176x384 bf16
  u16* hidden = qkvB;                     // 50176x1536 bf16 (reuses qkv+attn space)
  float* xres = (float*)d_out;            // x + attn output, original token order

  wconv_t<<<(442368 + 255) / 256, 256, 0, stream>>>(qkvw, wqT, 384, 1152);
  wconv_t<<<(147456 + 255) / 256, 256, 0, stream>>>(projw, wpT, 384, 384);
  wconv_t<<<(589824 + 255) / 256, 256, 0, stream>>>(w1, w1T, 384, 1536);
  wconv_t<<<(589824 + 255) / 256, 256, 0, stream>>>(w2, w2T, 1536, 384);

  ln_kernel<true><<<12544, 256, 0, stream>>>(x, n1g, n1b, lnbuf);
  gemm_bt<0><<<dim3(9, 392), 256, 0, stream>>>(lnbuf, wqT, qkvb, nullptr, qkvB, 384);
  attn_kernel<<<6144, 128, 0, stream>>>(qkvB, rpb, attnO);
  gemm_bt<1><<<dim3(3, 392), 256, 0, stream>>>(attnO, wpT, projb, x, xres, 384);
  ln_kernel<false><<<12544, 256, 0, stream>>>(xres, n2g, n2b, lnbuf);
  gemm_bt<2><<<dim3(12, 392), 256, 0, stream>>>(lnbuf, w1T, b1, nullptr, hidden, 384);
  gemm_bt<3><<<dim3(3, 392), 256, 0, stream>>>(hidden, w2T, b2, xres, d_out, 1536);
}

// Round 14
// 657.246 us; speedup vs baseline: 1.0123x; 1.0123x over previous
//
#include <hip/hip_runtime.h>
#include <cstdint>
#include <cstddef>

typedef __attribute__((ext_vector_type(8))) short short8;
typedef __attribute__((ext_vector_type(4))) float f32x4;
typedef unsigned short u16;

#define CDIM 384

__device__ __forceinline__ u16 f2bf(float f) {
  union { float f; uint32_t u; } v; v.f = f;
  return (u16)((v.u + 0x7FFFu + ((v.u >> 16) & 1u)) >> 16);
}

// async global->LDS, 16B per lane (m97 pattern: linear LDS dest = wave base + lane*16)
__device__ __forceinline__ void glds16(const void* g, void* l) {
  __builtin_amdgcn_global_load_lds(
      (__attribute__((address_space(1))) void*)(g),
      (__attribute__((address_space(3))) void*)(l), 16, 0, 0);
}

// bijective XCD-chunking swizzle (m204): contiguous new-ids land on one XCD
__device__ __forceinline__ int xcd_swz(int orig, int nwg) {
  int q = nwg >> 3, r = nwg & 7;
  int x = orig & 7, i = orig >> 3;
  int base = (x < r) ? x * (q + 1) : r * (q + 1) + (x - r) * q;
  return base + i;
}

// ---- weight convert + transpose: Wt[n*K + k] = bf16(W[k*N + n]) ----
__global__ void wconv_t(const float* __restrict__ W, u16* __restrict__ Wt, int K, int N) {
  int i = blockIdx.x * 256 + threadIdx.x;
  if (i >= K * N) return;
  int k = i / N, n = i - k * N;
  Wt[(size_t)n * K + k] = f2bf(W[i]);
}

// ---- LayerNorm over 384, one wave per row; optional shift+window gather ----
template<bool GATHER>
__global__ __launch_bounds__(256) void ln_kernel(const float* __restrict__ X,
    const float* __restrict__ G, const float* __restrict__ Bp,
    u16* __restrict__ Y) {
  int wid = threadIdx.x >> 6, lane = threadIdx.x & 63;
  int row = blockIdx.x * 4 + wid;
  const float* xr = X + (size_t)row * CDIM;
  float4 a = ((const float4*)xr)[lane];
  float2 b = ((const float2*)xr)[128 + lane];
  float s1 = a.x + a.y + a.z + a.w + b.x + b.y;
  float s2 = a.x*a.x + a.y*a.y + a.z*a.z + a.w*a.w + b.x*b.x + b.y*b.y;
  #pragma unroll
  for (int m = 1; m < 64; m <<= 1) { s1 += __shfl_xor(s1, m, 64); s2 += __shfl_xor(s2, m, 64); }
  float mean = s1 * (1.0f / CDIM);
  float var  = s2 * (1.0f / CDIM) - mean * mean;
  float rstd = rsqrtf(var + 1e-5f);
  float4 g4 = ((const float4*)G)[lane];
  float2 g2 = ((const float2*)G)[128 + lane];
  float4 b4 = ((const float4*)Bp)[lane];
  float2 b2 = ((const float2*)Bp)[128 + lane];
  size_t orow = row;
  if (GATHER) {
    int bb = row / 3136, l = row - bb * 3136;
    int h = l / 56, w = l - h * 56;
    int hs = h - 3; if (hs < 0) hs += 56;
    int wsv = w - 3; if (wsv < 0) wsv += 56;
    int wi = (hs / 7) * 8 + (wsv / 7);
    int n = (hs % 7) * 7 + (wsv % 7);
    orow = (size_t)(bb * 64 + wi) * 49 + n;
  }
  u16* yr = Y + orow * CDIM;
  ushort4 o4;
  o4.x = f2bf((a.x - mean) * rstd * g4.x + b4.x);
  o4.y = f2bf((a.y - mean) * rstd * g4.y + b4.y);
  o4.z = f2bf((a.z - mean) * rstd * g4.z + b4.z);
  o4.w = f2bf((a.w - mean) * rstd * g4.w + b4.w);
  ((ushort4*)yr)[lane] = o4;
  ushort2 o2;
  o2.x = f2bf((b.x - mean) * rstd * g2.x + b2.x);
  o2.y = f2bf((b.y - mean) * rstd * g2.y + b2.y);
  ((ushort2*)yr)[128 + lane] = o2;
}

// ---- bf16 GEMM, A (M,K) row-major, Bt (N,K) row-major, 128x128 tile, BK=32 ----
// T2: bank-conflict-free fragment reads via PRE-SWIZZLED GLOBAL SOURCE
// (LDS dest stays linear per glds16 contract; rule #21 both-sides):
//   thread c stages global chunk (r=c>>2, q=(c&3)^((c>>3)&3)) -> LDS chunk c
//   reader finds (row,g) at LDS chunk row*4 + (g^((row>>1)&3))
// ds_read_b128 bank spread: 8 distinct 4-bank groups / 16 lanes = 2-way (free).
// T4: counted vmcnt keeps next-tile prefetch in flight across barriers.
// MODE 0: qkv scatter (bf16)   1: proj + x residual, window->token scatter (f32)
// MODE 2: GELU -> hidden bf16  3: + xres residual -> f32 out
template<int MODE>
__global__ __launch_bounds__(256) void gemm_bt(
    const u16* __restrict__ A, const u16* __restrict__ Bt,
    const float* __restrict__ bias, const float* __restrict__ extra,
    void* __restrict__ outp, int K) {
  __shared__ __align__(16) u16 As[2][4096];
  __shared__ __align__(16) u16 Bs[2][4096];
  int tid = threadIdx.x;
  int lane = tid & 63, wid = tid >> 6;
  int ln = lane & 15, g = lane >> 4;
  int wm = (wid >> 1) * 64, wn = (wid & 1) * 64;
  int gx = gridDim.x;
  int nwg = gx * gridDim.y;
  int id = xcd_swz(blockIdx.y * gx + blockIdx.x, nwg);
  int bn = id % gx, bm = id / gx;
  int rs = K >> 3;  // short8 per row
  const short8* Ag = (const short8*)(A + (size_t)bm * 128 * K);
  const short8* Bg = (const short8*)(Bt + (size_t)bn * 128 * K);
  int c0 = tid, c1 = tid + 256;
  int r0 = c0 >> 2, r1 = c1 >> 2;
  // source-side swizzle: q = (c&3) ^ ((c>>3)&3)
  int q0 = (c0 & 3) ^ ((c0 >> 3) & 3);
  int q1 = (c1 & 3) ^ ((c1 >> 3) & 3);
  // read-side xor (lane-constant: wm/mi*16 are multiples of 16)
  int xr = g ^ ((ln >> 1) & 3);
  f32x4 acc[4][4] = {};
  int nk = K >> 5;
  // prologue: issue tile-0 staging (4 loads in flight)
  glds16(&Ag[r0 * rs + q0], &((short8*)As[0])[c0]);
  glds16(&Ag[r1 * rs + q1], &((short8*)As[0])[c1]);
  glds16(&Bg[r0 * rs + q0], &((short8*)Bs[0])[c0]);
  glds16(&Bg[r1 * rs + q1], &((short8*)Bs[0])[c1]);
  int cur = 0;
  for (int kt = 0; kt < nk; ++kt) {
    bool pf = (kt + 1 < nk);
    if (pf) {
      int ko = (kt + 1) * 4;
      glds16(&Ag[r0 * rs + ko + q0], &((short8*)As[cur ^ 1])[c0]);
      glds16(&Ag[r1 * rs + ko + q1], &((short8*)As[cur ^ 1])[c1]);
      glds16(&Bg[r0 * rs + ko + q0], &((short8*)Bs[cur ^ 1])[c0]);
      glds16(&Bg[r1 * rs + ko + q1], &((short8*)Bs[cur ^ 1])[c1]);
    }
    // wait ONLY for the current tile's 4 loads; prefetch stays in flight (T4)
    if (pf) asm volatile("s_waitcnt vmcnt(4)" ::: "memory");
    else    asm volatile("s_waitcnt vmcnt(0)" ::: "memory");
    __builtin_amdgcn_s_barrier();   // all waves: cur tile resident in LDS
    short8 af[4], bf[4];
    #pragma unroll
    for (int mi = 0; mi < 4; ++mi) af[mi] = ((short8*)As[cur])[(wm + mi * 16 + ln) * 4 + xr];
    #pragma unroll
    for (int ni = 0; ni < 4; ++ni) bf[ni] = ((short8*)Bs[cur])[(wn + ni * 16 + ln) * 4 + xr];
    #pragma unroll
    for (int mi = 0; mi < 4; ++mi)
      #pragma unroll
      for (int ni = 0; ni < 4; ++ni)
        acc[mi][ni] = __builtin_amdgcn_mfma_f32_16x16x32_bf16(af[mi], bf[ni], acc[mi][ni], 0, 0, 0);
    asm volatile("s_waitcnt lgkmcnt(0)" ::: "memory");
    __builtin_amdgcn_s_barrier();   // ds_reads done -> next iter may overwrite buf[cur]
    cur ^= 1;
  }
  int Rbase = bm * 128 + wm + g * 4;
  int Cbase = bn * 128 + wn + ln;
  #pragma unroll
  for (int mi = 0; mi < 4; ++mi) {
    #pragma unroll
    for (int r = 0; r < 4; ++r) {
      int R = Rbase + mi * 16 + r;
      #pragma unroll
      for (int ni = 0; ni < 4; ++ni) {
        int Cc = Cbase + ni * 16;
        float v = acc[mi][ni][r] + bias[Cc];
        if (MODE == 0) {
          int w_ = R / 49, n = R - w_ * 49;
          int t = Cc / 384, rem = Cc - t * 384;
          int hh = rem >> 5, d = rem & 31;
          ((u16*)outp)[((size_t)(w_ * 3 + t) * 12 + hh) * 1568 + n * 32 + d] = f2bf(v);
        } else if (MODE == 1) {
          int w_ = R / 49, n = R - w_ * 49;
          int bb = w_ >> 6, wi = w_ & 63;
          int hs = (wi >> 3) * 7 + n / 7;
          int wsv = (wi & 7) * 7 + n % 7;
          int h2 = hs + 3; if (h2 >= 56) h2 -= 56;
          int w2 = wsv + 3; if (w2 >= 56) w2 -= 56;
          size_t idx = ((size_t)bb * 3136 + h2 * 56 + w2) * 384 + Cc;
          ((float*)outp)[idx] = extra[idx] + v;
        } else if (MODE == 2) {
          float gl = 0.5f * v * (1.0f + erff(v * 0.70710678118f));
          ((u16*)outp)[(size_t)R * 1536 + Cc] = f2bf(gl);
        } else {
          size_t idx = (size_t)R * 384 + Cc;
          ((float*)outp)[idx] = extra[idx] + v;
        }
      }
    }
  }
}

// ---- attention: 1 wave per (window, head); S^T = K*Q^T; O^T = V^T*P^T ----
__global__ __launch_bounds__(128) void attn_kernel(
    const u16* __restrict__ qkv, const float* __restrict__ rpb,
    u16* __restrict__ aout) {
  __shared__ __align__(16) u16 lds[2][10240];
  int wid = threadIdx.x >> 6, lane = threadIdx.x & 63;
  int task = blockIdx.x * 2 + wid;
  int w_ = task / 12, hh = task - w_ * 12;
  int wi = w_ & 63;
  u16* Q  = lds[wid];
  u16* Kt = Q + 2048;
  u16* Vt = Q + 4096;
  u16* P  = Q + 6144;
  const short8* qb = (const short8*)(qkv + ((size_t)w_ * 36 + hh) * 1568);
  const short8* kb = (const short8*)(qkv + ((size_t)w_ * 36 + 12 + hh) * 1568);
  const short8* vb = (const short8*)(qkv + ((size_t)w_ * 36 + 24 + hh) * 1568);
  short8 zz = {0, 0, 0, 0, 0, 0, 0, 0};
  for (int c = 196 + lane; c < 256; c += 64) { ((short8*)Q)[c] = zz; ((short8*)Kt)[c] = zz; }
  for (int c = lane; c < 256; c += 64) ((short8*)Vt)[c] = zz;
  __syncthreads();
  for (int c = lane; c < 196; c += 64) {
    ((short8*)Q)[c]  = qb[c];
    ((short8*)Kt)[c] = kb[c];
    short8 vv = vb[c];
    int n = c >> 2, d0 = (c & 3) << 3;
    #pragma unroll
    for (int j = 0; j < 8; ++j) Vt[(d0 + j) * 64 + n] = (u16)vv[j];
  }
  __syncthreads();
  int ln = lane & 15, g = lane >> 4;
  short8 ak[4], bq[4];
  #pragma unroll
  for (int mi = 0; mi < 4; ++mi) ak[mi] = ((const short8*)Kt)[(mi * 16 + ln) * 4 + g];
  #pragma unroll
  for (int ni = 0; ni < 4; ++ni) bq[ni] = ((const short8*)Q)[(ni * 16 + ln) * 4 + g];
  f32x4 zf = {0.f, 0.f, 0.f, 0.f};
  f32x4 s[4][4];
  #pragma unroll
  for (int mi = 0; mi < 4; ++mi)
    #pragma unroll
    for (int ni = 0; ni < 4; ++ni)
      s[mi][ni] = __builtin_amdgcn_mfma_f32_16x16x32_bf16(ak[mi], bq[ni], zf, 0, 0, 0);
  const float scale = 0.17677669529663687f;  // 1/sqrt(32)
  int hb = (wi >> 3) * 7, wb = (wi & 7) * 7;
  #pragma unroll
  for (int ni = 0; ni < 4; ++ni) {
    int n = ni * 16 + ln;
    bool nv = n < 49;
    int nh = n / 7, nw = n - nh * 7;
    int hsn = hb + nh, wsn = wb + nw;
    int rn = (hsn < 49 ? 0 : (hsn < 53 ? 1 : 2)) * 3 + (wsn < 49 ? 0 : (wsn < 53 ? 1 : 2));
    float pv[16];
    float mx = -3.0e38f;
    #pragma unroll
    for (int mi = 0; mi < 4; ++mi) {
      #pragma unroll
      for (int r = 0; r < 4; ++r) {
        int m = mi * 16 + g * 4 + r;
        float v = -1.0e9f;
        if (nv && m < 49) {
          int mh = m / 7, mw = m - mh * 7;
          int hsm = hb + mh, wsm = wb + mw;
          int rm = (hsm < 49 ? 0 : (hsm < 53 ? 1 : 2)) * 3 + (wsm < 49 ? 0 : (wsm < 53 ? 1 : 2));
          int rel = (nh - mh + 6) * 13 + (nw - mw + 6);
          v = s[mi][ni][r] * scale + rpb[rel * 12 + hh];
          if (rn != rm) v -= 100.0f;
        }
        pv[mi * 4 + r] = v;
        mx = fmaxf(mx, v);
      }
    }
    mx = fmaxf(mx, __shfl_xor(mx, 16, 64));
    mx = fmaxf(mx, __shfl_xor(mx, 32, 64));
    float sum = 0.f;
    #pragma unroll
    for (int i = 0; i < 16; ++i) { pv[i] = __expf(pv[i] - mx); sum += pv[i]; }
    sum += __shfl_xor(sum, 16, 64);
    sum += __shfl_xor(sum, 32, 64);
    float inv = 1.0f / sum;
    #pragma unroll
    for (int mi = 0; mi < 4; ++mi) {
      ushort4 pk;
      pk.x = f2bf(pv[mi * 4 + 0] * inv);
      pk.y = f2bf(pv[mi * 4 + 1] * inv);
      pk.z = f2bf(pv[mi * 4 + 2] * inv);
      pk.w = f2bf(pv[mi * 4 + 3] * inv);
      *(ushort4*)(P + n * 64 + mi * 16 + g * 4) = pk;
    }
  }
  __syncthreads();
  f32x4 o[2][4] = {};
  #pragma unroll
  for (int kt = 0; kt < 2; ++kt) {
    short8 av[2], bp[4];
    #pragma unroll
    for (int m2 = 0; m2 < 2; ++m2) av[m2] = ((const short8*)Vt)[(m2 * 16 + ln) * 8 + kt * 4 + g];
    #pragma unroll
    for (int ni = 0; ni < 4; ++ni) bp[ni] = ((const short8*)P)[(ni * 16 + ln) * 8 + kt * 4 + g];
    #pragma unroll
    for (int m2 = 0; m2 < 2; ++m2)
      #pragma unroll
      for (int ni = 0; ni < 4; ++ni)
        o[m2][ni] = __builtin_amdgcn_mfma_f32_16x16x32_bf16(av[m2], bp[ni], o[m2][ni], 0, 0, 0);
  }
  #pragma unroll
  for (int m2 = 0; m2 < 2; ++m2)
    #pragma unroll
    for (int ni = 0; ni < 4; ++ni)
      #pragma unroll
      for (int r = 0; r < 4; ++r) {
        int d = m2 * 16 + g * 4 + r;
        int n = ni * 16 + ln;
        if (n < 49)
          aout[((size_t)w_ * 49 + n) * 384 + hh * 32 + d] = f2bf(o[m2][ni][r]);
      }
}

extern "C" void kernel_launch(void* const* d_in, const int* in_sizes, int n_in,
                              void* d_out, int out_size, void* d_ws, size_t ws_size,
                              hipStream_t stream) {
  const float* x     = (const float*)d_in[0];
  const float* n1g   = (const float*)d_in[3];
  const float* n1b   = (const float*)d_in[4];
  const float* qkvw  = (const float*)d_in[5];
  const float* qkvb  = (const float*)d_in[6];
  const float* rpb   = (const float*)d_in[7];
  const float* projw = (const float*)d_in[8];
  const float* projb = (const float*)d_in[9];
  const float* n2g   = (const float*)d_in[10];
  const float* n2b   = (const float*)d_in[11];
  const float* w1    = (const float*)d_in[12];
  const float* b1    = (const float*)d_in[13];
  const float* w2    = (const float*)d_in[14];
  const float* b2    = (const float*)d_in[15];

  char* ws = (char*)d_ws;
  u16* wqT    = (u16*)(ws + 0);           // 1152x384
  u16* wpT    = (u16*)(ws + 884736);      // 384x384
  u16* w1T    = (u16*)(ws + 1179648);     // 1536x384
  u16* w2T    = (u16*)(ws + 2359296);     // 384x1536
  u16* lnbuf  = (u16*)(ws + 3538944);     // 50176x384 bf16
  u16* qkvB   = (u16*)(ws + 42074112);    // 1024x3x12x49x32 bf16
  u16* attnO  = (u16*)(ws + 157679616);   // 50176x384 bf16
  u16* hidden = qkvB;                     // 50176x1536 bf16 (reuses qkv+attn space)
  float* xres = (float*)d_out;            // x + attn output, original token order

  wconv_t<<<(442368 + 255) / 256, 256, 0, stream>>>(qkvw, wqT, 384, 1152);
  wconv_t<<<(147456 + 255) / 256, 256, 0, stream>>>(projw, wpT, 384, 384);
  wconv_t<<<(589824 + 255) / 256, 256, 0, stream>>>(w1, w1T, 384, 1536);
  wconv_t<<<(589824 + 255) / 256, 256, 0, stream>>>(w2, w2T, 1536, 384);

  ln_kernel<true><<<12544, 256, 0, stream>>>(x, n1g, n1b, lnbuf);
  gemm_bt<0><<<dim3(9, 392), 256, 0, stream>>>(lnbuf, wqT, qkvb, nullptr, qkvB, 384);
  attn_kernel<<<6144, 128, 0, stream>>>(qkvB, rpb, attnO);
  gemm_bt<1><<<dim3(3, 392), 256, 0, stream>>>(attnO, wpT, projb, x, xres, 384);
  ln_kernel<false><<<12544, 256, 0, stream>>>(xres, n2g, n2b, lnbuf);
  gemm_bt<2><<<dim3(12, 392), 256, 0, stream>>>(lnbuf, w1T, b1, nullptr, hidden, 384);
  gemm_bt<3><<<dim3(3, 392), 256, 0, stream>>>(hidden, w2T, b2, xres, d_out, 1536);
}